// Round 9
// baseline (642.256 us; speedup 1.0000x reference)
//
#include <hip/hip_runtime.h>

// ---------------------------------------------------------------------------
// QGroupLinear: y[m,n] = sum_k x[m,k] * (qw[n,k] * sw[n, k/G]) + bias[n]
// M=4096 (B*S), K=4096, N=11008, G=128.
// R11: GEMM = R7/R10 structure frozen (330 us, MfmaUtil 55%, 4 blocks/CU,
//     BK=64 two-barrier single-buffer, row-XOR swizzle, XCD swizzle,
//     nt Y-stores). ONE graft: s_setprio(1) around each 16-MFMA cluster —
//     4 independent blocks/CU give cross-block phase diversity (m191's
//     +4-7% regime; m190's null was 1-block lockstep).
//     Prep: single kernel, MLP=2 — each iter issues one x-chunk AND one
//     w-chunk load (independent, 2 in flight per thread), 16B lane-contig
//     loads, 8B stores, no divergent branch.
// Model (R10 post-mortem): total 632 = gemm 330 + prep ~100 + ~200 fixed
//     in-stream harness reset (invariant across 5 prep designs). This
//     round pressures the two attackable terms; if both null -> composite
//     floor reached.
// Measured map (gemm dur): BK32 432 | BK64 330-341 (best) | 8-phase ports
//     432/568 | 2-phase dbuf 455 | 256x128 tile 382 (occupancy cliff).
//     nt Y-stores: neutral (FETCH 508->516, dur flat). Lane-contig prep:
//     -28 us total.
// ---------------------------------------------------------------------------

typedef __attribute__((ext_vector_type(8))) short short8;
typedef __attribute__((ext_vector_type(4))) short short4v;
typedef __attribute__((ext_vector_type(4))) float floatx4;
typedef __attribute__((ext_vector_type(4))) float f32x4v;
typedef __attribute__((ext_vector_type(4))) int i32x4v;

__device__ __forceinline__ unsigned short f2bf_rne(float f) {
  union { float f; unsigned int u; } c;
  c.f = f;
  unsigned int u = c.u;
  u += 0x7FFFu + ((u >> 16) & 1u);   // round-to-nearest-even
  return (unsigned short)(u >> 16);
}

// ---- merged prep, MLP=2: per iter one x-chunk + one w-chunk ---------------
// x-chunks: c in [0, nx4): xb[c*4..] = bf16(x[c*4..]).
// w-chunks: c in [0, nw4): wb[c*4..] = bf16(qw[c*4..] * sw[group]).
// Loop to max(nx4, nw4); both loads issued back-to-back (independent).
// Requires K%4==0, G%4==0 (launcher-checked).
__global__ void prep_kernel(const float* __restrict__ x,
                            const int* __restrict__ qw,
                            const float* __restrict__ sw,
                            short* __restrict__ xb,
                            short* __restrict__ wb,
                            long nx4, long nw4,
                            int kq, int kqshift, int gq, int gqshift,
                            int ngroups) {
  long stride = (long)gridDim.x * blockDim.x;
  long cmax = nx4 > nw4 ? nx4 : nw4;
  for (long c = (long)blockIdx.x * blockDim.x + threadIdx.x;
       c < cmax; c += stride) {
    bool dox = c < nx4;
    bool dow = c < nw4;
    f32x4v a;
    i32x4v q;
    float s = 0.f;
    if (dox) a = __builtin_nontemporal_load((const f32x4v*)(x + c * 4));
    if (dow) {
      int n, kpi;
      if (kqshift >= 0) {
        n = (int)(c >> kqshift);
        kpi = (int)(c & (long)(kq - 1));
      } else {
        n = (int)(c / kq);
        kpi = (int)(c - (long)n * kq);
      }
      int g = (gqshift >= 0) ? (kpi >> gqshift) : (kpi / gq);
      s = sw[(long)n * ngroups + g];
      q = __builtin_nontemporal_load((const i32x4v*)(qw + c * 4));
    }
    if (dox) {
      short4v o;
      o[0] = (short)f2bf_rne(a[0]); o[1] = (short)f2bf_rne(a[1]);
      o[2] = (short)f2bf_rne(a[2]); o[3] = (short)f2bf_rne(a[3]);
      *(short4v*)(xb + c * 4) = o;
    }
    if (dow) {
      short4v o;
      o[0] = (short)f2bf_rne((float)q[0] * s);
      o[1] = (short)f2bf_rne((float)q[1] * s);
      o[2] = (short)f2bf_rne((float)q[2] * s);
      o[3] = (short)f2bf_rne((float)q[3] * s);
      *(short4v*)(wb + c * 4) = o;
    }
  }
}

// ---- bf16 MFMA GEMM: Y[M][N] = Xb[M][K] * Wb[N][K]^T + bias ---------------
// R7 structure (330-341 us, MfmaUtil 52-56%, 0 conflicts) + T5 setprio.
#define BM 128
#define BN 128
#define BK 64

__global__ __launch_bounds__(256, 4) void gemm_bt_kernel(
    const short* __restrict__ Xb,    // [M][K] bf16 bits
    const short* __restrict__ Wb,    // [N][K] bf16 bits
    const float* __restrict__ bias,  // [N]
    float* __restrict__ Y,           // [M][N]
    int M, int N, int K) {
  __shared__ short As[BM * BK];  // 16 KB
  __shared__ short Bs[BN * BK];  // 16 KB

  const int t = threadIdx.x;     // 0..255
  const int wave = t >> 6;       // 0..3
  const int lane = t & 63;
  const int wm = wave >> 1;      // 0..1 (m-half)
  const int wn = wave & 1;       // 0..1 (n-half)
  const int quad = lane >> 4;    // 0..3
  const int l16 = lane & 15;

  // ---- XCD-aware swizzle: xcd = bid%8 owns M-tile stripe, sweeps N.
  const int gn = gridDim.x, gm = gridDim.y;
  int mt, nt;
  if ((gm & 7) == 0) {
    int stripe = gm >> 3;
    int bid = blockIdx.y * gn + blockIdx.x;
    int xcd = bid & 7;
    int q = bid >> 3;
    int msub = q % stripe;
    nt = q / stripe;
    mt = xcd * stripe + msub;
  } else {
    mt = blockIdx.y; nt = blockIdx.x;
  }
  const int tileM = mt * BM;
  const int tileN = nt * BN;

  floatx4 acc[4][4];
#pragma unroll
  for (int i = 0; i < 4; i++)
#pragma unroll
    for (int j = 0; j < 4; j++) acc[i][j] = {0.f, 0.f, 0.f, 0.f};

  const short* Ag = Xb + (long)tileM * K;
  const short* Bg = Wb + (long)tileN * K;

  // fragment read: row r = (half)*64 + i*16 + l16, global chunk g = s*4+quad
  // -> physical chunk g ^ (r&7) = g ^ (l16&7). ks1 offset = c0 ^ 32 shorts.
  const int c0 = (quad ^ (l16 & 7)) << 3;    // shorts

  for (int k0 = 0; k0 < K; k0 += BK) {
    // stage: thread t fills physical chunks {t, 256+t, 512+t, 768+t} of each
    // operand; physical (r = c>>3, pc = c&7) holds global chunk pc ^ (r&7).
#pragma unroll
    for (int jj = 0; jj < 4; ++jj) {
      const int c = (jj << 8) | t;
      const int r = c >> 3;
      const int g = (c & 7) ^ (r & 7);
      __builtin_amdgcn_global_load_lds(
          (const __attribute__((address_space(1))) void*)(
              Ag + (long)r * K + k0 + (g << 3)),
          (__attribute__((address_space(3))) void*)(As + (c << 3)),
          16, 0, 0);
    }
#pragma unroll
    for (int jj = 0; jj < 4; ++jj) {
      const int c = (jj << 8) | t;
      const int r = c >> 3;
      const int g = (c & 7) ^ (r & 7);
      __builtin_amdgcn_global_load_lds(
          (const __attribute__((address_space(1))) void*)(
              Bg + (long)r * K + k0 + (g << 3)),
          (__attribute__((address_space(3))) void*)(Bs + (c << 3)),
          16, 0, 0);
    }
    __syncthreads();   // drains vmcnt: tile resident

    const short* Aw = As + wm * 64 * BK;
    const short* Bw = Bs + wn * 64 * BK;
#pragma unroll
    for (int s = 0; s < 2; ++s) {
      const int cs = c0 ^ (s << 5);
      short8 af[4], bf[4];
#pragma unroll
      for (int i = 0; i < 4; i++)
        af[i] = *(const short8*)(Aw + (i * 16 + l16) * BK + cs);
#pragma unroll
      for (int j = 0; j < 4; j++)
        bf[j] = *(const short8*)(Bw + (j * 16 + l16) * BK + cs);
      // T5: bias CU issue toward this wave's MFMA while other blocks'
      // waves (4 blocks/CU, independent phases) issue staging/addressing.
      __builtin_amdgcn_s_setprio(1);
#pragma unroll
      for (int i = 0; i < 4; i++)
#pragma unroll
        for (int j = 0; j < 4; j++)
          acc[i][j] = __builtin_amdgcn_mfma_f32_16x16x32_bf16(
              af[i], bf[j], acc[i][j], 0, 0, 0);
      __builtin_amdgcn_s_setprio(0);
    }
    __syncthreads();   // protect LDS before next stage (single buffer)
  }

  // epilogue: C/D layout col=lane&15 (n), row=quad*4+reg (m).
  const int mbase = tileM + wm * 64;
  const int nbase = tileN + wn * 64;
#pragma unroll
  for (int i = 0; i < 4; i++) {
#pragma unroll
    for (int j = 0; j < 4; j++) {
      int n = nbase + j * 16 + l16;
      float bv = bias[n];
#pragma unroll
      for (int r = 0; r < 4; r++) {
        int m = mbase + i * 16 + quad * 4 + r;
        __builtin_nontemporal_store(acc[i][j][r] + bv, Y + (long)m * N + n);
      }
    }
  }
}

// ---- fallback (only if ws too small / odd shapes): correct but slow -------
__global__ void naive_kernel(const float* __restrict__ x,
                             const int* __restrict__ qw,
                             const float* __restrict__ sw,
                             const float* __restrict__ bias,
                             float* __restrict__ y,
                             int M, int N, int K, int G) {
  long idx = (long)blockIdx.x * blockDim.x + threadIdx.x;
  if (idx >= (long)M * N) return;
  int m = (int)(idx / N), n = (int)(idx % N);
  int ng = K / G;
  float acc = 0.f;
  for (int g = 0; g < ng; g++) {
    float s = sw[(long)n * ng + g];
    float part = 0.f;
    for (int k = g * G; k < (g + 1) * G; k++)
      part += x[(long)m * K + k] * (float)qw[(long)n * K + k];
    acc += part * s;
  }
  y[idx] = acc + bias[n];
}

extern "C" void kernel_launch(void* const* d_in, const int* in_sizes, int n_in,
                              void* d_out, int out_size, void* d_ws, size_t ws_size,
                              hipStream_t stream) {
  const float* x = (const float*)d_in[0];
  const int* qw = (const int*)d_in[1];
  const float* sw = (const float*)d_in[2];
  const float* bias = (const float*)d_in[3];
  float* y = (float*)d_out;

  const int N = in_sizes[3];
  const int K = in_sizes[1] / N;
  const int M = in_sizes[0] / K;
  const int ngroups = in_sizes[2] / N;
  const int G = K / ngroups;

  const long MK = (long)M * K;
  const long NK = (long)N * K;
  const size_t need = (size_t)(MK + NK) * sizeof(short);

  if (ws_size < need || (M % BM) || (N % BN) || (K % BK) || (G % 4) ||
      (K % 4)) {
    long total = (long)M * N;
    naive_kernel<<<(unsigned)((total + 255) / 256), 256, 0, stream>>>(
        x, qw, sw, bias, y, M, N, K, G);
    return;
  }

  short* xb = (short*)d_ws;
  short* wb = xb + MK;

  const int kq = K / 4;        // 4-elem runs per row
  const int gq = G / 4;        // 4-elem runs per group
  int kqshift = ((kq & (kq - 1)) == 0) ? __builtin_ctz((unsigned)kq) : -1;
  int gqshift = ((gq & (gq - 1)) == 0) ? __builtin_ctz((unsigned)gq) : -1;

  prep_kernel<<<2048, 256, 0, stream>>>(x, qw, sw, xb, wb,
                                        MK / 4, NK / 4,
                                        kq, kqshift, gq, gqshift, ngroups);

  dim3 grid((unsigned)(N / BN), (unsigned)(M / BM));
  gemm_bt_kernel<<<grid, 256, 0, stream>>>(xb, wb, bias, y, M, N, K);
}